// Round 13
// baseline (945.104 us; speedup 1.0000x reference)
//
#include <hip/hip_runtime.h>
#include <hip/hip_bf16.h>

#define NN 2048
#define EE 65536
#define HH 8
#define CC 128
#define HC 1024
#define NEG_SLOPE 0.2f

// sortable-uint encoding for float atomicMax (handles negatives)
__device__ __forceinline__ unsigned fenc(float f) {
    unsigned u = __float_as_uint(f);
    return (u & 0x80000000u) ? ~u : (u | 0x80000000u);
}
__device__ __forceinline__ float fdec(unsigned e) {
    return (e & 0x80000000u) ? __uint_as_float(e ^ 0x80000000u) : __uint_as_float(~e);
}

// ---------------- CSC (by dst) + CSR (by src) degree count ----------------
__global__ void k_deg2(const int* __restrict__ ei, int* __restrict__ deg,
                       int* __restrict__ deg_r) {
    int e = blockIdx.x * 256 + threadIdx.x;
    atomicAdd(&deg[ei[EE + e]], 1);    // CSC: by dst
    atomicAdd(&deg_r[ei[e]], 1);       // CSR: by src
}

__global__ void k_scan(const int* __restrict__ deg, int* __restrict__ offs) {
    __shared__ int buf[2][NN];
    int t = threadIdx.x; // 1024 threads
    for (int i = t; i < NN; i += 1024) buf[0][i] = deg[i];
    __syncthreads();
    int cur = 0;
    for (int off = 1; off < NN; off <<= 1) {
        for (int i = t; i < NN; i += 1024) {
            int v = buf[cur][i];
            if (i >= off) v += buf[cur][i - off];
            buf[cur ^ 1][i] = v;
        }
        __syncthreads();
        cur ^= 1;
    }
    if (t == 0) offs[0] = 0;
    for (int i = t; i < NN; i += 1024) offs[i + 1] = buf[cur][i];
}

__global__ void k_scatter(const int* __restrict__ ei, const int* __restrict__ offs,
                          int* __restrict__ cursor, int* __restrict__ elist) {
    int e = blockIdx.x * 256 + threadIdx.x;
    int d = ei[EE + e];
    int p = atomicAdd(&cursor[d], 1);
    elist[offs[d] + p] = e;
}

__global__ void k_scatter_r(const int* __restrict__ ei, const int* __restrict__ roffs,
                            int* __restrict__ cursor_r, unsigned short* __restrict__ csr_dst,
                            int* __restrict__ csr_eid) {
    int e = blockIdx.x * 256 + threadIdx.x;
    int s = ei[e], d = ei[EE + e];
    int p = atomicAdd(&cursor_r[s], 1);
    csr_dst[roffs[s] + p] = (unsigned short)d;
    csr_eid[roffs[s] + p] = e;
}

// csrc[slot] = src node of CSC-ordered edge slot (u16)
__global__ void k_csrc(const int* __restrict__ ei, const int* __restrict__ elist,
                       unsigned short* __restrict__ csrc) {
    int i = blockIdx.x * 256 + threadIdx.x;
    csrc[i] = (unsigned short)ei[elist[i]];
}

// ---------------- fused mask: per-row sparse walk-sum, norm, edge extraction ----
// Block s computes row s of R = I+A+A^2+A^3+A^4 (A = I+adj) in LDS via
// w_t = e_s + w_{t-1} A, with (wA)[j] = w[j] + sum_{(i,j) in E} w[i] (CSC).
// Then mask_e[eid] = w4[dst]/||w4|| for s's out-edges (CSR).
__global__ __launch_bounds__(256) void k_mask_rows(
    const int* __restrict__ offs, const unsigned short* __restrict__ csrc,
    const int* __restrict__ roffs, const unsigned short* __restrict__ csr_dst,
    const int* __restrict__ csr_eid, float* __restrict__ mask_e) {
    int s = blockIdx.x, t = threadIdx.x;
    __shared__ float w[2][NN];       // 16KB double buffer
    __shared__ int soffs[NN + 1];    // 8KB CSC offsets
    __shared__ float red[256];
    for (int i = t; i < NN + 1; i += 256) soffs[i] = offs[i];
    for (int i = t; i < NN; i += 256) w[0][i] = (i == s) ? 1.f : 0.f;
    __syncthreads();
    int cur = 0;
    for (int it = 0; it < 4; it++) {
        for (int j = t; j < NN; j += 256) {
            float acc = w[cur][j] + ((j == s) ? 1.f : 0.f);
            int b = soffs[j], e2 = soffs[j + 1];
            for (int c = b; c < e2; c++) acc += w[cur][csrc[c]];
            w[cur ^ 1][j] = acc;
        }
        __syncthreads();
        cur ^= 1;
    }
    // norm of row s (exact integers -> fp32 exact up to 2^24)
    float ss = 0.f;
    for (int j = t; j < NN; j += 256) { float v = w[cur][j]; ss += v * v; }
    red[t] = ss; __syncthreads();
    for (int o = 128; o > 0; o >>= 1) {
        if (t < o) red[t] += red[t + o];
        __syncthreads();
    }
    float rnorm = 1.0f / fmaxf(sqrtf(red[0]), 1e-12f);
    int rb = roffs[s], re = roffs[s + 1];
    for (int c = rb + t; c < re; c += 256)
        mask_e[csr_eid[c]] = w[cur][csr_dst[c]] * rnorm;
}

// ---------------- GEMM: C[2048,Ncols] = A[2048,128] * B[Ncols,128]^T (+bias) ----------------
__global__ __launch_bounds__(256) void gemm_nt(
    const float* __restrict__ A, const float* __restrict__ B,
    const float* __restrict__ bias, float* __restrict__ Cout, int Ncols) {
    __shared__ float As[64][132];
    __shared__ float Bt[128][68];
    int m0 = blockIdx.x * 64, n0 = blockIdx.y * 64;
    int t = threadIdx.x;
    for (int i = t; i < 64 * 32; i += 256) {        // A tile: 64 rows x 32 float4
        int r = i >> 5, c4 = i & 31;
        float4 v = *(const float4*)(A + (size_t)(m0 + r) * 128 + c4 * 4);
        *(float4*)&As[r][c4 * 4] = v;
    }
    for (int i = t; i < 64 * 32; i += 256) {        // B tile, transposed into Bt[k][n]
        int r = i >> 5, c4 = i & 31;
        float4 v = *(const float4*)(B + (size_t)(n0 + r) * 128 + c4 * 4);
        Bt[c4 * 4 + 0][r] = v.x;
        Bt[c4 * 4 + 1][r] = v.y;
        Bt[c4 * 4 + 2][r] = v.z;
        Bt[c4 * 4 + 3][r] = v.w;
    }
    __syncthreads();
    int ty = t >> 4, tx = t & 15;                   // 16 x 16
    float acc[4][4] = {};
    for (int k = 0; k < 128; k += 4) {
        float4 b0 = *(const float4*)&Bt[k + 0][tx * 4];
        float4 b1 = *(const float4*)&Bt[k + 1][tx * 4];
        float4 b2 = *(const float4*)&Bt[k + 2][tx * 4];
        float4 b3 = *(const float4*)&Bt[k + 3][tx * 4];
#pragma unroll
        for (int r = 0; r < 4; r++) {
            float4 a = *(const float4*)&As[ty * 4 + r][k];
            acc[r][0] += a.x * b0.x + a.y * b1.x + a.z * b2.x + a.w * b3.x;
            acc[r][1] += a.x * b0.y + a.y * b1.y + a.z * b2.y + a.w * b3.y;
            acc[r][2] += a.x * b0.z + a.y * b1.z + a.z * b2.z + a.w * b3.z;
            acc[r][3] += a.x * b0.w + a.y * b1.w + a.z * b2.w + a.w * b3.w;
        }
    }
#pragma unroll
    for (int r = 0; r < 4; r++) {
        int col = n0 + tx * 4;
        float4 o = make_float4(acc[r][0], acc[r][1], acc[r][2], acc[r][3]);
        if (bias) {
            o.x += bias[col + 0]; o.y += bias[col + 1];
            o.z += bias[col + 2]; o.w += bias[col + 3];
        }
        *(float4*)(Cout + (size_t)(m0 + ty * 4 + r) * Ncols + col) = o;
    }
}

// ---------------- attention scores s_i, s_j ----------------
__global__ void k_scores(const float* __restrict__ xh, const float* __restrict__ att,
                         float* __restrict__ s_i, float* __restrict__ s_j) {
    int n = blockIdx.x, t = threadIdx.x;
    int h = t >> 5, lane = t & 31;
    const float* xr = xh + (size_t)n * HC + h * CC;
    const float* at = att + h * 2 * CC;
    float ai = 0.f, aj = 0.f;
    for (int c = lane; c < CC; c += 32) {
        float xv = xr[c];
        ai += xv * at[c];
        aj += xv * at[CC + c];
    }
#pragma unroll
    for (int o = 16; o > 0; o >>= 1) {
        ai += __shfl_xor(ai, o);
        aj += __shfl_xor(aj, o);
    }
    if (lane == 0) {
        s_i[n * HH + h] = ai;
        s_j[n * HH + h] = aj;
    }
}

// ---------------- per-edge logits + per-head block max -> global atomicMax ----------------
__global__ __launch_bounds__(256) void k_alpha_z(
    const int* __restrict__ ei, const float* __restrict__ s_i,
    const float* __restrict__ s_j, const float* __restrict__ mask_e,
    float* __restrict__ zbuf, unsigned* __restrict__ gmax) {
    int t = threadIdx.x;
    int e = blockIdx.x * 256 + t;
    int s = ei[e], d = ei[EE + e];
    float me = mask_e[e];
    float4 di0 = *(const float4*)(s_i + d * HH);
    float4 di1 = *(const float4*)(s_i + d * HH + 4);
    float4 sj0 = *(const float4*)(s_j + s * HH);
    float4 sj1 = *(const float4*)(s_j + s * HH + 4);
    float z[8] = {di0.x + sj0.x, di0.y + sj0.y, di0.z + sj0.z, di0.w + sj0.w,
                  di1.x + sj1.x, di1.y + sj1.y, di1.z + sj1.z, di1.w + sj1.w};
    __shared__ float smax[HH][256];
#pragma unroll
    for (int h = 0; h < 8; h++) {
        float v = z[h];
        v = (v >= 0.f) ? v : NEG_SLOPE * v;
        v *= me;
        zbuf[(size_t)h * EE + e] = v;
        smax[h][t] = v;
    }
    __syncthreads();
    for (int s2 = 128; s2 > 0; s2 >>= 1) {
        if (t < s2) {
#pragma unroll
            for (int h = 0; h < 8; h++)
                smax[h][t] = fmaxf(smax[h][t], smax[h][t + s2]);
        }
        __syncthreads();
    }
    if (t < 8) atomicMax(&gmax[t], fenc(smax[t][0]));
}

// ---------------- parallel sum of exp(z - mx) per head ----------------
__global__ __launch_bounds__(256) void k_softmax_sum(
    const float* __restrict__ zbuf, const unsigned* __restrict__ gmax,
    float* __restrict__ gsum) {
    int h = blockIdx.y, t = threadIdx.x;
    float mx = fdec(gmax[h]);
    const float* z = zbuf + (size_t)h * EE + blockIdx.x * 2048;
    float s = 0.f;
#pragma unroll
    for (int i = 0; i < 8; i++) s += expf(z[t + i * 256] - mx);
    __shared__ float red[256];
    red[t] = s; __syncthreads();
    for (int s2 = 128; s2 > 0; s2 >>= 1) {
        if (t < s2) red[t] += red[t + s2];
        __syncthreads();
    }
    if (t == 0) atomicAdd(&gsum[h], red[0]);
}

__global__ void k_finalize_stats(const unsigned* __restrict__ gmax,
                                 const float* __restrict__ gsum,
                                 float* __restrict__ stats) {
    int t = threadIdx.x; // 8 threads
    stats[t] = fdec(gmax[t]);
    stats[HH + t] = 1.0f / gsum[t];
}

// ---------------- aggregate, 2x-src-unrolled for MLP ----------------
__global__ __launch_bounds__(256) void k_aggregate(
    const float* __restrict__ xh, const float* __restrict__ zbuf,
    const float* __restrict__ stats, const int* __restrict__ offs,
    const int* __restrict__ elist, const int* __restrict__ ei,
    const float* __restrict__ skip, float* __restrict__ outp, int final_layer) {
    int d = blockIdx.x, t = threadIdx.x;
    int hh = t >> 7, c = t & 127;
    __shared__ float sw[32][8];
    __shared__ int ssrc[32];
    __shared__ float combine[128];
    float acc = 0.f;
    int beg = offs[d], end = offs[d + 1];
    for (int base = beg; base < end; base += 32) {
        int m = min(32, end - base);
        __syncthreads();
        if (t < m) ssrc[t] = ei[elist[base + t]];
        if (t < m * 8) {
            int k = t >> 3, h = t & 7;
            int e = elist[base + k];
            float z = zbuf[(size_t)h * EE + e];
            sw[k][h] = expf(z - stats[h]) * stats[HH + h];
        }
        __syncthreads();
        int k = 0;
        for (; k + 2 <= m; k += 2) {    // 8 independent loads in flight
            const float* x0 = xh + (size_t)ssrc[k] * HC + c;
            const float* x1 = xh + (size_t)ssrc[k + 1] * HC + c;
            float a0 = x0[hh * 128], a1 = x0[(hh + 2) * 128];
            float a2 = x0[(hh + 4) * 128], a3 = x0[(hh + 6) * 128];
            float b0 = x1[hh * 128], b1 = x1[(hh + 2) * 128];
            float b2 = x1[(hh + 4) * 128], b3 = x1[(hh + 6) * 128];
            acc += a0 * sw[k][hh] + a1 * sw[k][hh + 2] +
                   a2 * sw[k][hh + 4] + a3 * sw[k][hh + 6] +
                   b0 * sw[k + 1][hh] + b1 * sw[k + 1][hh + 2] +
                   b2 * sw[k + 1][hh + 4] + b3 * sw[k + 1][hh + 6];
        }
        if (k < m) {
            const float* x0 = xh + (size_t)ssrc[k] * HC + c;
            acc += x0[hh * 128] * sw[k][hh] + x0[(hh + 2) * 128] * sw[k][hh + 2] +
                   x0[(hh + 4) * 128] * sw[k][hh + 4] + x0[(hh + 6) * 128] * sw[k][hh + 6];
        }
    }
    if (hh == 0) combine[c] = acc;
    __syncthreads();
    if (hh == 1) combine[c] += acc;
    __syncthreads();
    if (hh == 0) {
        float v = fmaxf(combine[c] * 0.125f, 0.f); // mean over 8 heads + relu
        if (final_layer) v += skip[(size_t)d * CC + c];
        outp[(size_t)d * CC + c] = v;
    }
}

extern "C" void kernel_launch(void* const* d_in, const int* in_sizes, int n_in,
                              void* d_out, int out_size, void* d_ws, size_t ws_size,
                              hipStream_t stream) {
    const float* x    = (const float*)d_in[0];
    const int*   ei   = (const int*)d_in[1];
    const float* w0   = (const float*)d_in[2];
    const float* att0 = (const float*)d_in[3];
    const float* w1   = (const float*)d_in[4];
    const float* att1 = (const float*)d_in[5];
    const float* skw  = (const float*)d_in[6];
    const float* skb  = (const float*)d_in[7];
    float* outp = (float*)d_out;

    char* p = (char*)d_ws;
    auto alloc = [&](size_t bytes) {
        char* r = p;
        p += (bytes + 255) & ~(size_t)255;
        return r;
    };
    float* xh     = (float*)alloc((size_t)NN * HC * 4);
    float* h1     = (float*)alloc((size_t)NN * CC * 4);
    float* xskip  = (float*)alloc((size_t)NN * CC * 4);
    float* zbuf   = (float*)alloc((size_t)HH * EE * 4);
    float* mask_e = (float*)alloc((size_t)EE * 4);
    float* s_i    = (float*)alloc((size_t)NN * HH * 4);
    float* s_j    = (float*)alloc((size_t)NN * HH * 4);
    float* stats  = (float*)alloc(64);
    unsigned* gmax = (unsigned*)alloc(HH * 4);
    float* gsum   = (float*)alloc(HH * 4);
    int* deg      = (int*)alloc((size_t)NN * 4);
    int* deg_r    = (int*)alloc((size_t)NN * 4);
    int* offs     = (int*)alloc((size_t)(NN + 1) * 4);
    int* roffs    = (int*)alloc((size_t)(NN + 1) * 4);
    int* cursor   = (int*)alloc((size_t)NN * 4);
    int* cursor_r = (int*)alloc((size_t)NN * 4);
    int* elist    = (int*)alloc((size_t)EE * 4);
    int* csr_eid  = (int*)alloc((size_t)EE * 4);
    unsigned short* csrc    = (unsigned short*)alloc((size_t)EE * 2);
    unsigned short* csr_dst = (unsigned short*)alloc((size_t)EE * 2);

    hipMemsetAsync(deg, 0, (size_t)NN * 4, stream);
    hipMemsetAsync(deg_r, 0, (size_t)NN * 4, stream);
    hipMemsetAsync(cursor, 0, (size_t)NN * 4, stream);
    hipMemsetAsync(cursor_r, 0, (size_t)NN * 4, stream);

    // CSC + CSR build
    k_deg2<<<EE / 256, 256, 0, stream>>>(ei, deg, deg_r);
    k_scan<<<1, 1024, 0, stream>>>(deg, offs);
    k_scan<<<1, 1024, 0, stream>>>(deg_r, roffs);
    k_scatter<<<EE / 256, 256, 0, stream>>>(ei, offs, cursor, elist);
    k_scatter_r<<<EE / 256, 256, 0, stream>>>(ei, roffs, cursor_r, csr_dst, csr_eid);
    k_csrc<<<EE / 256, 256, 0, stream>>>(ei, elist, csrc);

    // fused mask: per-row sparse walk-sum + norm + edge extraction
    k_mask_rows<<<NN, 256, 0, stream>>>(offs, csrc, roffs, csr_dst, csr_eid, mask_e);

    // skip connection
    gemm_nt<<<dim3(32, 2), 256, 0, stream>>>(x, skw, skb, xskip, 128);

    // layer 1
    gemm_nt<<<dim3(32, 16), 256, 0, stream>>>(x, w0, nullptr, xh, 1024);
    k_scores<<<NN, 256, 0, stream>>>(xh, att0, s_i, s_j);
    hipMemsetAsync(gmax, 0, HH * 4, stream);
    hipMemsetAsync(gsum, 0, HH * 4, stream);
    k_alpha_z<<<EE / 256, 256, 0, stream>>>(ei, s_i, s_j, mask_e, zbuf, gmax);
    k_softmax_sum<<<dim3(32, HH), 256, 0, stream>>>(zbuf, gmax, gsum);
    k_finalize_stats<<<1, HH, 0, stream>>>(gmax, gsum, stats);
    k_aggregate<<<NN, 256, 0, stream>>>(xh, zbuf, stats, offs, elist, ei, nullptr, h1, 0);

    // layer 2 (+ skip, write d_out)
    gemm_nt<<<dim3(32, 16), 256, 0, stream>>>(h1, w1, nullptr, xh, 1024);
    k_scores<<<NN, 256, 0, stream>>>(xh, att1, s_i, s_j);
    hipMemsetAsync(gmax, 0, HH * 4, stream);
    hipMemsetAsync(gsum, 0, HH * 4, stream);
    k_alpha_z<<<EE / 256, 256, 0, stream>>>(ei, s_i, s_j, mask_e, zbuf, gmax);
    k_softmax_sum<<<dim3(32, HH), 256, 0, stream>>>(zbuf, gmax, gsum);
    k_finalize_stats<<<1, HH, 0, stream>>>(gmax, gsum, stats);
    k_aggregate<<<NN, 256, 0, stream>>>(xh, zbuf, stats, offs, elist, ei, xskip, outp, 1);
}

// Round 14
// 348.987 us; speedup vs baseline: 2.7081x; 2.7081x over previous
//
#include <hip/hip_runtime.h>
#include <hip/hip_bf16.h>

#define NN 2048
#define EE 65536
#define HH 8
#define CC 128
#define HC 1024
#define NEG_SLOPE 0.2f

// sortable-uint encoding for float atomicMax (handles negatives)
__device__ __forceinline__ unsigned fenc(float f) {
    unsigned u = __float_as_uint(f);
    return (u & 0x80000000u) ? ~u : (u | 0x80000000u);
}
__device__ __forceinline__ float fdec(unsigned e) {
    return (e & 0x80000000u) ? __uint_as_float(e ^ 0x80000000u) : __uint_as_float(~e);
}

// ---------------- CSC build ----------------
__global__ void k_deg(const int* __restrict__ ei, int* __restrict__ deg) {
    int e = blockIdx.x * 256 + threadIdx.x;
    atomicAdd(&deg[ei[EE + e]], 1);
}

__global__ void k_scan(const int* __restrict__ deg, int* __restrict__ offs) {
    __shared__ int buf[2][NN];
    int t = threadIdx.x; // 1024 threads
    for (int i = t; i < NN; i += 1024) buf[0][i] = deg[i];
    __syncthreads();
    int cur = 0;
    for (int off = 1; off < NN; off <<= 1) {
        for (int i = t; i < NN; i += 1024) {
            int v = buf[cur][i];
            if (i >= off) v += buf[cur][i - off];
            buf[cur ^ 1][i] = v;
        }
        __syncthreads();
        cur ^= 1;
    }
    if (t == 0) offs[0] = 0;
    for (int i = t; i < NN; i += 1024) offs[i + 1] = buf[cur][i];
}

__global__ void k_scatter(const int* __restrict__ ei, const int* __restrict__ offs,
                          int* __restrict__ cursor, int* __restrict__ elist) {
    int e = blockIdx.x * 256 + threadIdx.x;
    int d = ei[EE + e];
    int p = atomicAdd(&cursor[d], 1);
    elist[offs[d] + p] = e;
}

// ---------------- M = I + A + A^2 built directly from sparse CSC (u16 out) ----------------
__global__ __launch_bounds__(256) void k_build_M(
    const int* __restrict__ offs, const int* __restrict__ elist,
    const int* __restrict__ ei, unsigned short* __restrict__ M) {
    int d = blockIdx.x, t = threadIdx.x;
    __shared__ float col[NN];      // 8KB dense column accumulator
    __shared__ int s_b[256], s_l[256];
    for (int i = t; i < NN; i += 256) col[i] = 0.f;
    int beg = offs[d], end = offs[d + 1];
    for (int base = beg; base < end; base += 256) {
        int m = min(256, end - base);
        __syncthreads();           // orders col init / prev chunk before restage
        if (t < m) {
            int s = ei[elist[base + t]];
            int b = offs[s];
            s_b[t] = b;
            s_l[t] = offs[s + 1] - b;
            atomicAdd(&col[s], 3.0f);
        }
        __syncthreads();
        for (int i = 0; i < m; i++) {
            int b = s_b[i], l = s_l[i];
            for (int j = t; j < l; j += 256) {
                int u = ei[elist[b + j]];
                atomicAdd(&col[u], 1.0f);
            }
        }
    }
    __syncthreads();
    if (t == 0) col[d] += 3.0f;
    __syncthreads();
    for (int i = t; i < NN; i += 256) M[(size_t)d * NN + i] = (unsigned short)col[i];
}

// ---------------- row-sliced gather on u16 matrices (halved fabric traffic) ----------------
template <int EDGE_ADD, int DIAG_ADD>
__global__ __launch_bounds__(256) void k_gather(
    const unsigned short* __restrict__ Kin, unsigned short* __restrict__ Kout,
    const int* __restrict__ offs, const int* __restrict__ elist,
    const int* __restrict__ ei) {
    int d = blockIdx.x, t = threadIdx.x;
    int row0 = blockIdx.y * 256;   // thread t owns row row0+t
    __shared__ int ssrc[256];
    __shared__ float extra[256];
    if (EDGE_ADD) extra[t] = 0.f;
    const unsigned short* Kr = Kin + row0 + t;
    float acc = (float)Kr[(size_t)d * NN];
    int beg = offs[d], end = offs[d + 1];
    for (int base = beg; base < end; base += 256) {
        int m = min(256, end - base);
        __syncthreads();           // orders extra init / prev-chunk reads before restage
        if (t < m) {
            int s = ei[elist[base + t]];
            ssrc[t] = s;
            if (EDGE_ADD) {
                int ls = s - row0;
                if (ls >= 0 && ls < 256) atomicAdd(&extra[ls], (float)EDGE_ADD);
            }
        }
        __syncthreads();
        int k = 0;
        for (; k + 4 <= m; k += 4) {   // 4 independent loads in flight
            float v0 = (float)Kr[(size_t)ssrc[k + 0] * NN];
            float v1 = (float)Kr[(size_t)ssrc[k + 1] * NN];
            float v2 = (float)Kr[(size_t)ssrc[k + 2] * NN];
            float v3 = (float)Kr[(size_t)ssrc[k + 3] * NN];
            acc += v0 + v1 + v2 + v3;
        }
        for (; k < m; k++) acc += (float)Kr[(size_t)ssrc[k] * NN];
    }
    if (DIAG_ADD && (d - row0) == t) acc += (float)DIAG_ADD;
    if (EDGE_ADD) {
        __syncthreads();
        acc += extra[t];
    }
    Kout[(size_t)d * NN + row0 + t] = (unsigned short)acc;
}

__global__ void k_norm2(const unsigned short* __restrict__ R, float* __restrict__ norm2) {
    int i = blockIdx.x * 256 + threadIdx.x; // row
    int j0 = blockIdx.y * 128;
    float s = 0.f;
    for (int j = j0; j < j0 + 128; j++) {
        float v = (float)R[(size_t)j * NN + i];
        s += v * v;
    }
    atomicAdd(&norm2[i], s);
}

__global__ void k_mask(const int* __restrict__ ei, const unsigned short* __restrict__ R,
                       const float* __restrict__ norm2, float* __restrict__ mask_e) {
    int e = blockIdx.x * 256 + threadIdx.x;
    int s = ei[e], d = ei[EE + e];
    float r = (float)R[(size_t)d * NN + s];
    float nrm = sqrtf(norm2[s]);
    mask_e[e] = r / fmaxf(nrm, 1e-12f);
}

// ---------------- GEMM: C[2048,Ncols] = A[2048,128] * B[Ncols,128]^T (+bias) ----------------
__global__ __launch_bounds__(256) void gemm_nt(
    const float* __restrict__ A, const float* __restrict__ B,
    const float* __restrict__ bias, float* __restrict__ Cout, int Ncols) {
    __shared__ float As[64][132];
    __shared__ float Bt[128][68];
    int m0 = blockIdx.x * 64, n0 = blockIdx.y * 64;
    int t = threadIdx.x;
    for (int i = t; i < 64 * 32; i += 256) {        // A tile: 64 rows x 32 float4
        int r = i >> 5, c4 = i & 31;
        float4 v = *(const float4*)(A + (size_t)(m0 + r) * 128 + c4 * 4);
        *(float4*)&As[r][c4 * 4] = v;
    }
    for (int i = t; i < 64 * 32; i += 256) {        // B tile, transposed into Bt[k][n]
        int r = i >> 5, c4 = i & 31;
        float4 v = *(const float4*)(B + (size_t)(n0 + r) * 128 + c4 * 4);
        Bt[c4 * 4 + 0][r] = v.x;
        Bt[c4 * 4 + 1][r] = v.y;
        Bt[c4 * 4 + 2][r] = v.z;
        Bt[c4 * 4 + 3][r] = v.w;
    }
    __syncthreads();
    int ty = t >> 4, tx = t & 15;                   // 16 x 16
    float acc[4][4] = {};
    for (int k = 0; k < 128; k += 4) {
        float4 b0 = *(const float4*)&Bt[k + 0][tx * 4];
        float4 b1 = *(const float4*)&Bt[k + 1][tx * 4];
        float4 b2 = *(const float4*)&Bt[k + 2][tx * 4];
        float4 b3 = *(const float4*)&Bt[k + 3][tx * 4];
#pragma unroll
        for (int r = 0; r < 4; r++) {
            float4 a = *(const float4*)&As[ty * 4 + r][k];
            acc[r][0] += a.x * b0.x + a.y * b1.x + a.z * b2.x + a.w * b3.x;
            acc[r][1] += a.x * b0.y + a.y * b1.y + a.z * b2.y + a.w * b3.y;
            acc[r][2] += a.x * b0.z + a.y * b1.z + a.z * b2.z + a.w * b3.z;
            acc[r][3] += a.x * b0.w + a.y * b1.w + a.z * b2.w + a.w * b3.w;
        }
    }
#pragma unroll
    for (int r = 0; r < 4; r++) {
        int col = n0 + tx * 4;
        float4 o = make_float4(acc[r][0], acc[r][1], acc[r][2], acc[r][3]);
        if (bias) {
            o.x += bias[col + 0]; o.y += bias[col + 1];
            o.z += bias[col + 2]; o.w += bias[col + 3];
        }
        *(float4*)(Cout + (size_t)(m0 + ty * 4 + r) * Ncols + col) = o;
    }
}

// ---------------- attention scores s_i, s_j ----------------
__global__ void k_scores(const float* __restrict__ xh, const float* __restrict__ att,
                         float* __restrict__ s_i, float* __restrict__ s_j) {
    int n = blockIdx.x, t = threadIdx.x;
    int h = t >> 5, lane = t & 31;
    const float* xr = xh + (size_t)n * HC + h * CC;
    const float* at = att + h * 2 * CC;
    float ai = 0.f, aj = 0.f;
    for (int c = lane; c < CC; c += 32) {
        float xv = xr[c];
        ai += xv * at[c];
        aj += xv * at[CC + c];
    }
#pragma unroll
    for (int o = 16; o > 0; o >>= 1) {
        ai += __shfl_xor(ai, o);
        aj += __shfl_xor(aj, o);
    }
    if (lane == 0) {
        s_i[n * HH + h] = ai;
        s_j[n * HH + h] = aj;
    }
}

// ---------------- per-edge logits + per-head block max -> global atomicMax ----------------
__global__ __launch_bounds__(256) void k_alpha_z(
    const int* __restrict__ ei, const float* __restrict__ s_i,
    const float* __restrict__ s_j, const float* __restrict__ mask_e,
    float* __restrict__ zbuf, unsigned* __restrict__ gmax) {
    int t = threadIdx.x;
    int e = blockIdx.x * 256 + t;
    int s = ei[e], d = ei[EE + e];
    float me = mask_e[e];
    float4 di0 = *(const float4*)(s_i + d * HH);
    float4 di1 = *(const float4*)(s_i + d * HH + 4);
    float4 sj0 = *(const float4*)(s_j + s * HH);
    float4 sj1 = *(const float4*)(s_j + s * HH + 4);
    float z[8] = {di0.x + sj0.x, di0.y + sj0.y, di0.z + sj0.z, di0.w + sj0.w,
                  di1.x + sj1.x, di1.y + sj1.y, di1.z + sj1.z, di1.w + sj1.w};
    __shared__ float smax[HH][256];
#pragma unroll
    for (int h = 0; h < 8; h++) {
        float v = z[h];
        v = (v >= 0.f) ? v : NEG_SLOPE * v;
        v *= me;
        zbuf[(size_t)h * EE + e] = v;
        smax[h][t] = v;
    }
    __syncthreads();
    for (int s2 = 128; s2 > 0; s2 >>= 1) {
        if (t < s2) {
#pragma unroll
            for (int h = 0; h < 8; h++)
                smax[h][t] = fmaxf(smax[h][t], smax[h][t + s2]);
        }
        __syncthreads();
    }
    if (t < 8) atomicMax(&gmax[t], fenc(smax[t][0]));
}

// ---------------- parallel sum of exp(z - mx) per head ----------------
__global__ __launch_bounds__(256) void k_softmax_sum(
    const float* __restrict__ zbuf, const unsigned* __restrict__ gmax,
    float* __restrict__ gsum) {
    int h = blockIdx.y, t = threadIdx.x;
    float mx = fdec(gmax[h]);
    const float* z = zbuf + (size_t)h * EE + blockIdx.x * 2048;
    float s = 0.f;
#pragma unroll
    for (int i = 0; i < 8; i++) s += expf(z[t + i * 256] - mx);
    __shared__ float red[256];
    red[t] = s; __syncthreads();
    for (int s2 = 128; s2 > 0; s2 >>= 1) {
        if (t < s2) red[t] += red[t + s2];
        __syncthreads();
    }
    if (t == 0) atomicAdd(&gsum[h], red[0]);
}

// ---------------- aggregate, 2x-src-unrolled; stats folded in (gmax/gsum direct) ----------------
__global__ __launch_bounds__(256) void k_aggregate(
    const float* __restrict__ xh, const float* __restrict__ zbuf,
    const unsigned* __restrict__ gmax, const float* __restrict__ gsum,
    const int* __restrict__ offs, const int* __restrict__ elist,
    const int* __restrict__ ei, const float* __restrict__ skip,
    float* __restrict__ outp, int final_layer) {
    int d = blockIdx.x, t = threadIdx.x;
    int hh = t >> 7, c = t & 127;
    __shared__ float sw[32][8];
    __shared__ int ssrc[32];
    __shared__ float combine[128];
    __shared__ float shh[8], srcp[8];
    if (t < 8) { shh[t] = fdec(gmax[t]); srcp[t] = 1.0f / gsum[t]; }
    float acc = 0.f;
    int beg = offs[d], end = offs[d + 1];
    for (int base = beg; base < end; base += 32) {
        int m = min(32, end - base);
        __syncthreads();
        if (t < m) ssrc[t] = ei[elist[base + t]];
        if (t < m * 8) {
            int k = t >> 3, h = t & 7;
            int e = elist[base + k];
            float z = zbuf[(size_t)h * EE + e];
            sw[k][h] = expf(z - shh[h]) * srcp[h];
        }
        __syncthreads();
        int k = 0;
        for (; k + 2 <= m; k += 2) {    // 8 independent loads in flight
            const float* x0 = xh + (size_t)ssrc[k] * HC + c;
            const float* x1 = xh + (size_t)ssrc[k + 1] * HC + c;
            float a0 = x0[hh * 128], a1 = x0[(hh + 2) * 128];
            float a2 = x0[(hh + 4) * 128], a3 = x0[(hh + 6) * 128];
            float b0 = x1[hh * 128], b1 = x1[(hh + 2) * 128];
            float b2 = x1[(hh + 4) * 128], b3 = x1[(hh + 6) * 128];
            acc += a0 * sw[k][hh] + a1 * sw[k][hh + 2] +
                   a2 * sw[k][hh + 4] + a3 * sw[k][hh + 6] +
                   b0 * sw[k + 1][hh] + b1 * sw[k + 1][hh + 2] +
                   b2 * sw[k + 1][hh + 4] + b3 * sw[k + 1][hh + 6];
        }
        if (k < m) {
            const float* x0 = xh + (size_t)ssrc[k] * HC + c;
            acc += x0[hh * 128] * sw[k][hh] + x0[(hh + 2) * 128] * sw[k][hh + 2] +
                   x0[(hh + 4) * 128] * sw[k][hh + 4] + x0[(hh + 6) * 128] * sw[k][hh + 6];
        }
    }
    if (hh == 0) combine[c] = acc;
    __syncthreads();
    if (hh == 1) combine[c] += acc;
    __syncthreads();
    if (hh == 0) {
        float v = fmaxf(combine[c] * 0.125f, 0.f); // mean over 8 heads + relu
        if (final_layer) v += skip[(size_t)d * CC + c];
        outp[(size_t)d * CC + c] = v;
    }
}

extern "C" void kernel_launch(void* const* d_in, const int* in_sizes, int n_in,
                              void* d_out, int out_size, void* d_ws, size_t ws_size,
                              hipStream_t stream) {
    const float* x    = (const float*)d_in[0];
    const int*   ei   = (const int*)d_in[1];
    const float* w0   = (const float*)d_in[2];
    const float* att0 = (const float*)d_in[3];
    const float* w1   = (const float*)d_in[4];
    const float* att1 = (const float*)d_in[5];
    const float* skw  = (const float*)d_in[6];
    const float* skb  = (const float*)d_in[7];
    float* outp = (float*)d_out;

    char* p = (char*)d_ws;
    auto alloc = [&](size_t bytes) {
        char* r = p;
        p += (bytes + 255) & ~(size_t)255;
        return r;
    };
    unsigned short* Ka = (unsigned short*)alloc((size_t)NN * NN * 2);
    unsigned short* Kb = (unsigned short*)alloc((size_t)NN * NN * 2);
    float* xh     = (float*)alloc((size_t)NN * HC * 4);
    float* h1     = (float*)alloc((size_t)NN * CC * 4);
    float* xskip  = (float*)alloc((size_t)NN * CC * 4);
    float* zbuf   = (float*)alloc((size_t)HH * EE * 4);
    float* mask_e = (float*)alloc((size_t)EE * 4);
    float* s_i    = (float*)alloc((size_t)NN * HH * 4);
    float* s_j    = (float*)alloc((size_t)NN * HH * 4);
    float* norm2  = (float*)alloc((size_t)NN * 4);
    unsigned* gmax = (unsigned*)alloc(HH * 4);   // gmax+gsum: adjacent 256B slots
    float* gsum   = (float*)alloc(HH * 4);
    int* deg    = (int*)alloc((size_t)NN * 4);   // deg+cursor: contiguous 16KB
    int* cursor = (int*)alloc((size_t)NN * 4);
    int* offs   = (int*)alloc((size_t)(NN + 1) * 4);
    int* elist  = (int*)alloc((size_t)EE * 4);

    hipMemsetAsync(deg, 0, (size_t)2 * NN * 4, stream);   // deg + cursor
    hipMemsetAsync(norm2, 0, (size_t)NN * 4, stream);

    // CSC build
    k_deg<<<EE / 256, 256, 0, stream>>>(ei, deg);
    k_scan<<<1, 1024, 0, stream>>>(deg, offs);
    k_scatter<<<EE / 256, 256, 0, stream>>>(ei, offs, cursor, elist);

    // mask: M = I+A+A^2 (sparse build, u16), T = M*A, R = I + A + T*A
    k_build_M<<<NN, 256, 0, stream>>>(offs, elist, ei, Ka);
    k_gather<0, 0><<<dim3(NN, 8), 256, 0, stream>>>(Ka, Kb, offs, elist, ei);
    k_gather<1, 2><<<dim3(NN, 8), 256, 0, stream>>>(Kb, Ka, offs, elist, ei);
    k_norm2<<<dim3(NN / 256, 16), 256, 0, stream>>>(Ka, norm2);
    k_mask<<<EE / 256, 256, 0, stream>>>(ei, Ka, norm2, mask_e);

    // skip connection
    gemm_nt<<<dim3(32, 2), 256, 0, stream>>>(x, skw, skb, xskip, 128);

    // layer 1
    gemm_nt<<<dim3(32, 16), 256, 0, stream>>>(x, w0, nullptr, xh, 1024);
    k_scores<<<NN, 256, 0, stream>>>(xh, att0, s_i, s_j);
    hipMemsetAsync(gmax, 0, 512, stream);   // gmax + gsum slots
    k_alpha_z<<<EE / 256, 256, 0, stream>>>(ei, s_i, s_j, mask_e, zbuf, gmax);
    k_softmax_sum<<<dim3(32, HH), 256, 0, stream>>>(zbuf, gmax, gsum);
    k_aggregate<<<NN, 256, 0, stream>>>(xh, zbuf, gmax, gsum, offs, elist, ei, nullptr, h1, 0);

    // layer 2 (+ skip, write d_out)
    gemm_nt<<<dim3(32, 16), 256, 0, stream>>>(h1, w1, nullptr, xh, 1024);
    k_scores<<<NN, 256, 0, stream>>>(xh, att1, s_i, s_j);
    hipMemsetAsync(gmax, 0, 512, stream);
    k_alpha_z<<<EE / 256, 256, 0, stream>>>(ei, s_i, s_j, mask_e, zbuf, gmax);
    k_softmax_sum<<<dim3(32, HH), 256, 0, stream>>>(zbuf, gmax, gsum);
    k_aggregate<<<NN, 256, 0, stream>>>(xh, zbuf, gmax, gsum, offs, elist, ei, xskip, outp, 1);
}